// Round 7
// baseline (61.042 us; speedup 1.0000x reference)
//
#include <hip/hip_runtime.h>
#include <stdint.h>

#define DIM    1024
#define NEXP   20
#define NFRQ   3000
#define TOPK   5
#define BATCH  64

#define CHUNKS       16
#define CHUNK_ELEMS  (DIM * DIM / CHUNKS)   // 65536 elems (2^16)
#define CHUNK_WORDS  (CHUNK_ELEMS / 32)     // 2048 words = 8 KiB LDS bitmap

typedef float    f32x4 __attribute__((ext_vector_type(4)));
typedef uint32_t u32x4 __attribute__((ext_vector_type(4)));

// Single fused kernel: 1024 blocks x 512 threads; block (b, chunk) owns one
// contiguous 256 KiB slice of output row b. No cross-block dependencies:
// each block redundantly computes row b's router top-5 (20 dots of 1024;
// W = 80 KB, L2-resident after first touch), then membership-scans the 5
// selected index tables (5 x 3000 coalesced L2 loads, hit rate 1/16) into an
// 8 KiB LDS bitmap, then streams the chunk out as coalesced plain float4.
// Every output byte is written exactly once; OR is commutative and the
// top-5 (strict >, smaller-index tie-break == jax.lax.top_k; softmax is
// monotonic) is deterministic -> output deterministic.
__global__ __launch_bounds__(512)
void fused_kernel(const float* __restrict__ cls, const float* __restrict__ W,
                  const float* __restrict__ bias,
                  const int* __restrict__ list_indices,
                  f32x4* __restrict__ out) {
    const int t     = threadIdx.x;              // 0..511
    const int b     = blockIdx.x >> 4;          // 0..63
    const int chunk = blockIdx.x & (CHUNKS - 1);

    __shared__ uint32_t bm[CHUNK_WORDS];        // 8 KiB
    __shared__ float    red[512];               // 2 KiB
    __shared__ int      experts[TOPK];

    // zero bitmap (independent of router work, same pass)
    ((u32x4*)bm)[t] = (u32x4){0u, 0u, 0u, 0u};  // 512*16B = 8 KiB exactly

    // ---- router: logits for row b (redundant per block, W is L2-hot) ----
    {
        const int e = t & 31;                   // expert lane (e<20 valid)
        const int r = t >> 5;                   // 0..15, 64 dims each
        const float* x = cls + (size_t)b * DIM;
        float acc = 0.0f;
        if (e < NEXP) {
            #pragma unroll 8
            for (int i = 0; i < DIM / 16; ++i) {        // 64 MACs
                const int d = r * (DIM / 16) + i;
                acc += x[d] * W[(size_t)d * NEXP + e];  // 20-consecutive/group
            }
        }
        red[t] = acc;
    }
    __syncthreads();

    // ---- wave-parallel top-5 (wave 0) ----
    if (t < 64) {
        float v = -INFINITY;
        int   idx = t;
        if (t < NEXP) {
            v = bias[t];
            #pragma unroll
            for (int rr = 0; rr < 16; ++rr) v += red[rr * 32 + t];
        }
        #pragma unroll
        for (int k = 0; k < TOPK; ++k) {
            float bv = v; int bi = idx;
            #pragma unroll
            for (int off = 32; off >= 1; off >>= 1) {
                const float ov = __shfl_xor(bv, off);
                const int   oi = __shfl_xor(bi, off);
                if (ov > bv || (ov == bv && oi < bi)) { bv = ov; bi = oi; }
            }
            if (t == 0) experts[k] = bi;
            if (idx == bi) v = -INFINITY;       // remove winner
        }
    }
    __syncthreads();

    // ---- membership scan: set bits of this chunk from the 5 tables ----
    #pragma unroll
    for (int k = 0; k < TOPK; ++k) {
        const int* tbl = list_indices + (size_t)experts[k] * NFRQ;
        for (int f = t; f < NFRQ; f += 512) {          // 6 coalesced iters
            const int idx = tbl[f];
            if ((idx >> 16) == chunk)                  // CHUNK_ELEMS = 2^16
                atomicOr(&bm[(idx & (CHUNK_ELEMS - 1)) >> 5], 1u << (idx & 31));
        }
    }
    __syncthreads();

    // ---- stream the 256 KiB chunk out, written exactly once ----
    f32x4* dst = out + (size_t)b * (DIM * DIM / 4)
                     + (size_t)chunk * (CHUNK_ELEMS / 4);
    #pragma unroll 8
    for (int i = 0; i < CHUNK_ELEMS / 4 / 512; ++i) {  // 32 float4/thread
        const int j = t + i * 512;
        const uint32_t wv = bm[j >> 3];                // 8-lane broadcast
        const uint32_t s  = ((uint32_t)j & 7u) * 4u;
        f32x4 v;
        v.x = ((wv >> (s + 0)) & 1u) ? 1.0f : 0.0f;
        v.y = ((wv >> (s + 1)) & 1u) ? 1.0f : 0.0f;
        v.z = ((wv >> (s + 2)) & 1u) ? 1.0f : 0.0f;
        v.w = ((wv >> (s + 3)) & 1u) ? 1.0f : 0.0f;
        dst[j] = v;                                    // plain store
    }
}

extern "C" void kernel_launch(void* const* d_in, const int* in_sizes, int n_in,
                              void* d_out, int out_size, void* d_ws, size_t ws_size,
                              hipStream_t stream) {
    const float* cls          = (const float*)d_in[0];  // [64,1024]
    const float* W            = (const float*)d_in[1];  // [1024,20]
    const float* bias         = (const float*)d_in[2];  // [20]
    const int*   list_indices = (const int*)d_in[3];    // [20,3000]

    fused_kernel<<<dim3(BATCH * CHUNKS), dim3(512), 0, stream>>>(
        cls, W, bias, list_indices, (f32x4*)d_out);
}